// Round 9
// baseline (166.486 us; speedup 1.0000x reference)
//
#include <hip/hip_runtime.h>

#define HH 128
#define WW 128
#define HWSZ (HH * WW)
#define CC 64
#define OO 64
#define BB 4
#define NOFF 18
#define KK 576          // C*9
#define EPS 1e-5f

// ws layout (dword offsets)
#define WS_BG     0                         // 72*64*4 = 18432 (deform weights, quad-packed)
#define WS_BGO    18432                     // 72*32*4 = 9216  (offset weights, quad-packed, N=32)
#define WS_SUMS   27648                     // 64
#define WS_SUMSQ  27712                     // 64
#define WS_YBUF   27776                     // 4*64*16384 = 4194304

typedef __attribute__((ext_vector_type(8))) short short8;
typedef __attribute__((ext_vector_type(4))) int int4v;
typedef __attribute__((ext_vector_type(4))) float f32x4;
typedef __attribute__((ext_vector_type(2))) float f32x2;

__device__ inline unsigned bf16rne(float f) {
  unsigned u = __float_as_uint(f);
  u += 0x7fff + ((u >> 16) & 1);
  return u >> 16;
}
// unpack a packed bf16 pair into float2 {lo, hi}
__device__ inline f32x2 up2(unsigned d) {
  f32x2 r;
  r.x = __uint_as_float(d << 16);
  r.y = __uint_as_float(d & 0xffff0000u);
  return r;
}
// pack float2 -> bf16 pair (round-to-nearest, ties away), one v_perm
__device__ inline unsigned pk2(f32x2 s) {
  return __builtin_amdgcn_perm(__float_as_uint(s.y) + 0x8000u,
                               __float_as_uint(s.x) + 0x8000u, 0x07060302u);
}

// prep: NHWC-bf16 transpose (bid<512) + weight repack + stats zero (bid 512..575).
// K order: k = t*64 + c. Pair k2 = t*32 + jj packs channels (2jj,2jj+1).
// Quad-packed B: k-quad g (k2 = g*4+j): Bg[(g*64+o)*4+j], Bgo[(g*32+o)*4+j].
__global__ __launch_bounds__(256) void prep_kernel(
    const float* __restrict__ x, const float* __restrict__ off_w,
    const float* __restrict__ dc_w, unsigned int* __restrict__ xTu,
    int* __restrict__ Bg, int* __restrict__ Bgo, float* __restrict__ sums) {
  __shared__ float T[CC][WW + 1];
  int bid = blockIdx.x;
  if (bid < BB * HH) {
    int b = bid >> 7, h = bid & 127;
    int tw = threadIdx.x & 127, th = threadIdx.x >> 7;
    const float* xp = x + (size_t)b * CC * HWSZ + h * WW;
#pragma unroll 8
    for (int i = 0; i < 32; ++i) {
      int c = i * 2 + th;
      T[c][tw] = xp[c * HWSZ + tw];
    }
    __syncthreads();
    int c2 = threadIdx.x & 31, wq = threadIdx.x >> 5;
    unsigned int* op = xTu + ((size_t)(b * HH + h) * WW) * 32;
#pragma unroll 8
    for (int i = 0; i < 16; ++i) {
      int w = i * 8 + wq;
      unsigned pk = bf16rne(T[2 * c2][w]) | (bf16rne(T[2 * c2 + 1][w]) << 16);
      op[w * 32 + c2] = pk;
    }
  } else {
    int t0 = (bid - BB * HH) * 256 + threadIdx.x;
    const int stride = 64 * 256;
    for (int i = t0; i < 72 * 64 * 4; i += stride) {
      int j = i & 3, o = (i >> 2) & 63, g = i >> 8;
      int k2 = g * 4 + j, t = k2 >> 5, jj = k2 & 31;
      unsigned lo = bf16rne(dc_w[o * KK + (2 * jj) * 9 + t]);
      unsigned hi = bf16rne(dc_w[o * KK + (2 * jj + 1) * 9 + t]);
      Bg[i] = (int)(lo | (hi << 16));
    }
    for (int i = t0; i < 72 * 32 * 4; i += stride) {
      int j = i & 3, o = (i >> 2) & 31, g = i >> 7;
      int k2 = g * 4 + j, t = k2 >> 5, jj = k2 & 31;
      unsigned pk = 0;
      if (o < NOFF) {
        unsigned lo = bf16rne(off_w[o * KK + (2 * jj) * 9 + t]);
        unsigned hi = bf16rne(off_w[o * KK + (2 * jj + 1) * 9 + t]);
        pk = lo | (hi << 16);
      }
      Bgo[i] = (int)pk;
    }
    if (t0 < 128) sums[t0] = 0.0f;   // sums + sumsq contiguous
  }
}

// Fused offset-conv + deform-conv + BN-stats, all-register im2col:
// lane (n16,q) at k-step (t,s) needs NHWC dwords c2 = s*16+q*4+{0..3} of
// pixel n16, tap t -> gather dwordx4 corners, bilinear-combine in registers,
// feed MFMA directly. No A tile in LDS at all.
__global__ __launch_bounds__(256) void conv_kernel(
    const unsigned int* __restrict__ xTu, const int* __restrict__ Bg,
    const int* __restrict__ Bgo, const float* __restrict__ off_b,
    const float* __restrict__ dc_b, float* __restrict__ ybuf,
    float* __restrict__ sums, float* __restrict__ sumsq) {
  __shared__ __align__(16) int M[4 * 144 * 4];    // 9.2 KB bilinear meta
  __shared__ float offL[4][NOFF][16];             // 4.6 KB offsets
  __shared__ float Ssum[256], Ssq[256];           // 2 KB stats

  int cg = threadIdx.x >> 6, lane = threadIdx.x & 63;
  int b = blockIdx.x >> 8, rem = blockIdx.x & 255;
  int h = rem >> 1, w0 = (rem & 1) * 64;
  int hw0 = h * WW + w0;
  int p0 = cg * 16;
  int n16 = lane & 15, q = lane >> 4;
  const unsigned int* xbu = xTu + (size_t)b * HWSZ * 32;

  // ---------- phase 1: offset conv, direct-register im2col ----------
  f32x4 acc2[2] = {f32x4{0, 0, 0, 0}, f32x4{0, 0, 0, 0}};
  int cxp = w0 + p0 + n16 - 1;
#pragma unroll 1
  for (int chunk = 0; chunk < 3; ++chunk) {
    int cy = h + chunk - 1;
    bool vy = (cy >= 0) && (cy < HH);
    int cys = min(max(cy, 0), HH - 1);
#pragma unroll
    for (int tl = 0; tl < 3; ++tl) {
      int cx = cxp + tl;
      bool v = vy && (cx >= 0) && (cx < WW);
      int cxs = min(max(cx, 0), WW - 1);
      const unsigned int* src = xbu + (cys * WW + cxs) * 32 + q * 4;
      int t = chunk * 3 + tl;
#pragma unroll
      for (int s = 0; s < 2; ++s) {
        int4v av = *(const int4v*)(src + s * 16);
        if (!v) { av.x = 0; av.y = 0; av.z = 0; av.w = 0; }
        short8 af = __builtin_bit_cast(short8, av);
        int g = (t * 2 + s) * 4 + q;
#pragma unroll
        for (int nt = 0; nt < 2; ++nt) {
          int4v bv = *(const int4v*)&Bgo[(g * 32 + nt * 16 + n16) * 4];
          short8 bfr = __builtin_bit_cast(short8, bv);
          acc2[nt] = __builtin_amdgcn_mfma_f32_16x16x32_bf16(af, bfr, acc2[nt], 0, 0, 0);
        }
      }
    }
  }
#pragma unroll
  for (int nt = 0; nt < 2; ++nt) {
    int o = nt * 16 + n16;
    if (o < NOFF) {
      float bv = off_b[o];
#pragma unroll
      for (int r = 0; r < 4; ++r) offL[cg][o][q * 4 + r] = acc2[nt][r] + bv;
    }
  }

  // ---------- phase 2: bilinear meta (wave-private) ----------
  int* Mw = M + cg * 144 * 4;
#pragma unroll
  for (int it = 0; it < 3; ++it) {
    int m = it * 64 + lane;
    if (m < 144) {
      int pxl = (unsigned)m / 9u;
      int t = m - pxl * 9;
      float dy = offL[cg][2 * t][pxl];
      float dx = offL[cg][2 * t + 1][pxl];
      float py = (float)(h + t / 3 - 1) + dy;
      float pxf = (float)(w0 + p0 + pxl + (t % 3) - 1) + dx;
      float fy0 = floorf(py), fx0 = floorf(pxf);
      float ay = py - fy0, ax = pxf - fx0;
      int iy0 = (int)fy0, ix0 = (int)fx0;
      int iy1 = iy0 + 1, ix1 = ix0 + 1;
      float wy0 = 1.0f - ay, wy1 = ay, wx0 = 1.0f - ax, wx1 = ax;
      if (!(iy0 >= 0 && iy0 < HH)) wy0 = 0.0f;
      if (!(iy1 >= 0 && iy1 < HH)) wy1 = 0.0f;
      if (!(ix0 >= 0 && ix0 < WW)) wx0 = 0.0f;
      if (!(ix1 >= 0 && ix1 < WW)) wx1 = 0.0f;
      int cy0 = min(max(iy0, 0), HH - 1), cy1 = min(max(iy1, 0), HH - 1);
      int cx0 = min(max(ix0, 0), WW - 1), cx1 = min(max(ix1, 0), WW - 1);
      int4v mv;
      mv.x = (cy0 * WW + cx0) | ((cy0 * WW + cx1) << 16);
      mv.y = (cy1 * WW + cx0) | ((cy1 * WW + cx1) << 16);
      mv.z = (int)(bf16rne(wy0 * wx0) | (bf16rne(wy0 * wx1) << 16));
      mv.w = (int)(bf16rne(wy1 * wx0) | (bf16rne(wy1 * wx1) << 16));
      *(int4v*)&Mw[m * 4] = mv;
    }
  }

  // ---------- phase 3: deform conv, register gather + bilinear + MFMA ----------
  f32x4 acc[4] = {f32x4{0,0,0,0}, f32x4{0,0,0,0}, f32x4{0,0,0,0}, f32x4{0,0,0,0}};
#pragma unroll 1
  for (int t = 0; t < 9; ++t) {
    int4v mv = *(const int4v*)&Mw[(n16 * 9 + t) * 4];   // q lanes broadcast
    unsigned o00 = mv.x & 0xffff, o01 = ((unsigned)mv.x) >> 16;
    unsigned o10 = mv.y & 0xffff, o11 = ((unsigned)mv.y) >> 16;
    f32x2 w00; w00.x = __uint_as_float(((unsigned)mv.z) << 16);        w00.y = w00.x;
    f32x2 w01; w01.x = __uint_as_float(((unsigned)mv.z) & 0xffff0000u); w01.y = w01.x;
    f32x2 w10; w10.x = __uint_as_float(((unsigned)mv.w) << 16);        w10.y = w10.x;
    f32x2 w11; w11.x = __uint_as_float(((unsigned)mv.w) & 0xffff0000u); w11.y = w11.x;
    const unsigned int* p00 = xbu + o00 * 32 + q * 4;
    const unsigned int* p01 = xbu + o01 * 32 + q * 4;
    const unsigned int* p10 = xbu + o10 * 32 + q * 4;
    const unsigned int* p11 = xbu + o11 * 32 + q * 4;
#pragma unroll
    for (int s = 0; s < 2; ++s) {
      int4v d00 = *(const int4v*)(p00 + s * 16);
      int4v d01 = *(const int4v*)(p01 + s * 16);
      int4v d10 = *(const int4v*)(p10 + s * 16);
      int4v d11 = *(const int4v*)(p11 + s * 16);
      int4v av;
      {
        f32x2 sc = up2(d00.x) * w00;
        sc = up2(d01.x) * w01 + sc;
        sc = up2(d10.x) * w10 + sc;
        sc = up2(d11.x) * w11 + sc;
        av.x = (int)pk2(sc);
      }
      {
        f32x2 sc = up2(d00.y) * w00;
        sc = up2(d01.y) * w01 + sc;
        sc = up2(d10.y) * w10 + sc;
        sc = up2(d11.y) * w11 + sc;
        av.y = (int)pk2(sc);
      }
      {
        f32x2 sc = up2(d00.z) * w00;
        sc = up2(d01.z) * w01 + sc;
        sc = up2(d10.z) * w10 + sc;
        sc = up2(d11.z) * w11 + sc;
        av.z = (int)pk2(sc);
      }
      {
        f32x2 sc = up2(d00.w) * w00;
        sc = up2(d01.w) * w01 + sc;
        sc = up2(d10.w) * w10 + sc;
        sc = up2(d11.w) * w11 + sc;
        av.w = (int)pk2(sc);
      }
      short8 af = __builtin_bit_cast(short8, av);
      int g = (t * 2 + s) * 4 + q;
#pragma unroll
      for (int nt = 0; nt < 4; ++nt) {
        int4v bv = *(const int4v*)&Bg[(g * 64 + nt * 16 + n16) * 4];
        short8 bfr = __builtin_bit_cast(short8, bv);
        acc[nt] = __builtin_amdgcn_mfma_f32_16x16x32_bf16(af, bfr, acc[nt], 0, 0, 0);
      }
    }
  }

  // ---------- epilogue: y store + stats reduce ----------
#pragma unroll
  for (int nt = 0; nt < 4; ++nt) {
    int o = nt * 16 + n16;
    float bv = dc_b[o];
    float s = 0.0f, ss = 0.0f;
#pragma unroll
    for (int r0 = 0; r0 < 4; ++r0) {
      acc[nt][r0] += bv;
      s += acc[nt][r0];
      ss += acc[nt][r0] * acc[nt][r0];
    }
    *(f32x4*)(ybuf + (size_t)(b * OO + o) * HWSZ + hw0 + p0 + q * 4) = acc[nt];
    s += __shfl_xor(s, 16);  s += __shfl_xor(s, 32);
    ss += __shfl_xor(ss, 16); ss += __shfl_xor(ss, 32);
    if (lane < 16) {   // lane == n16
      Ssum[cg * 64 + nt * 16 + lane] = s;
      Ssq[cg * 64 + nt * 16 + lane] = ss;
    }
  }
  __syncthreads();
  if (threadIdx.x < 64) {
    float ts = 0.0f, tq = 0.0f;
#pragma unroll
    for (int wv = 0; wv < 4; ++wv) {
      ts += Ssum[wv * 64 + threadIdx.x];
      tq += Ssq[wv * 64 + threadIdx.x];
    }
    atomicAdd(&sums[threadIdx.x], ts);
    atomicAdd(&sumsq[threadIdx.x], tq);
  }
}

__global__ __launch_bounds__(256) void norm_kernel(
    const float* __restrict__ ybuf, const float* __restrict__ sums,
    const float* __restrict__ sumsq, const float* __restrict__ gamma,
    const float* __restrict__ beta, float* __restrict__ out) {
  int gid = blockIdx.x * 256 + threadIdx.x;
  int flat = gid << 2;
  int o = (flat >> 14) & 63;
  const float invN = 1.0f / (float)(BB * HWSZ);
  float mean = sums[o] * invN;
  float var = sumsq[o] * invN - mean * mean;
  float rstd = rsqrtf(var + EPS);
  float g = gamma[o] * rstd;
  float bta = beta[o] - mean * g;
  float4 v = ((const float4*)ybuf)[gid];
  float4 r;
  r.x = fmaxf(v.x * g + bta, 0.0f);
  r.y = fmaxf(v.y * g + bta, 0.0f);
  r.z = fmaxf(v.z * g + bta, 0.0f);
  r.w = fmaxf(v.w * g + bta, 0.0f);
  ((float4*)out)[gid] = r;
}

extern "C" void kernel_launch(void* const* d_in, const int* in_sizes, int n_in,
                              void* d_out, int out_size, void* d_ws, size_t ws_size,
                              hipStream_t stream) {
  const float* x     = (const float*)d_in[0];
  const float* off_w = (const float*)d_in[1];
  const float* off_b = (const float*)d_in[2];
  const float* dc_w  = (const float*)d_in[3];
  const float* dc_b  = (const float*)d_in[4];
  const float* gamma = (const float*)d_in[5];
  const float* beta  = (const float*)d_in[6];
  float* ws = (float*)d_ws;
  int*   Bg    = (int*)(ws + WS_BG);
  int*   Bgo   = (int*)(ws + WS_BGO);
  float* sums  = ws + WS_SUMS;
  float* sumsq = ws + WS_SUMSQ;
  float* ybuf  = ws + WS_YBUF;
  float* out = (float*)d_out;
  unsigned int* xTu = (unsigned int*)d_out;  // d_out doubles as NHWC-bf16 scratch

  prep_kernel<<<BB * HH + 64, 256, 0, stream>>>(x, off_w, dc_w, xTu, Bg, Bgo, sums);
  conv_kernel<<<BB * HWSZ / 64, 256, 0, stream>>>(xTu, Bg, Bgo, off_b, dc_b, ybuf, sums, sumsq);
  norm_kernel<<<BB * OO * HWSZ / (4 * 256), 256, 0, stream>>>(ybuf, sums, sumsq, gamma, beta, out);
}

// Round 10
// 153.470 us; speedup vs baseline: 1.0848x; 1.0848x over previous
//
#include <hip/hip_runtime.h>

#define HH 128
#define WW 128
#define HWSZ (HH * WW)
#define CC 64
#define OO 64
#define BB 4
#define NOFF 18
#define KK 576          // C*9
#define EPS 1e-5f

// ws layout (dword offsets)
#define WS_BG     0                         // 72*64*4 = 18432 (deform weights, quad-packed)
#define WS_BGO    18432                     // 72*32*4 = 9216  (offset weights, quad-packed, N=32)
#define WS_SUMS   27648                     // 64
#define WS_SUMSQ  27712                     // 64
#define WS_YBUF   27776                     // 4*64*16384 = 4194304

typedef __attribute__((ext_vector_type(8))) short short8;
typedef __attribute__((ext_vector_type(4))) int int4v;
typedef __attribute__((ext_vector_type(4))) float f32x4;
typedef __attribute__((ext_vector_type(2))) float f32x2;

__device__ inline unsigned bf16rne(float f) {
  unsigned u = __float_as_uint(f);
  u += 0x7fff + ((u >> 16) & 1);
  return u >> 16;
}
// unpack a packed bf16 pair into float2 {lo, hi}
__device__ __forceinline__ f32x2 up2(unsigned d) {
  f32x2 r;
  r.x = __uint_as_float(d << 16);
  r.y = __uint_as_float(d & 0xffff0000u);
  return r;
}
// pack float2 -> bf16 pair (round-to-nearest, ties away), one v_perm
__device__ __forceinline__ unsigned pk2(f32x2 s) {
  return __builtin_amdgcn_perm(__float_as_uint(s.y) + 0x8000u,
                               __float_as_uint(s.x) + 0x8000u, 0x07060302u);
}

// prep: NHWC-bf16 transpose (bid<512) + weight repack + stats zero (bid 512..575).
// K order: k = t*64 + c. Pair k2 = t*32 + jj packs channels (2jj,2jj+1).
// Quad-packed B: k-quad g (k2 = g*4+j): Bg[(g*64+o)*4+j], Bgo[(g*32+o)*4+j].
__global__ __launch_bounds__(256) void prep_kernel(
    const float* __restrict__ x, const float* __restrict__ off_w,
    const float* __restrict__ dc_w, unsigned int* __restrict__ xTu,
    int* __restrict__ Bg, int* __restrict__ Bgo, float* __restrict__ sums) {
  __shared__ float T[CC][WW + 1];
  int bid = blockIdx.x;
  if (bid < BB * HH) {
    int b = bid >> 7, h = bid & 127;
    int tw = threadIdx.x & 127, th = threadIdx.x >> 7;
    const float* xp = x + (size_t)b * CC * HWSZ + h * WW;
#pragma unroll 8
    for (int i = 0; i < 32; ++i) {
      int c = i * 2 + th;
      T[c][tw] = xp[c * HWSZ + tw];
    }
    __syncthreads();
    int c2 = threadIdx.x & 31, wq = threadIdx.x >> 5;
    unsigned int* op = xTu + ((size_t)(b * HH + h) * WW) * 32;
#pragma unroll 8
    for (int i = 0; i < 16; ++i) {
      int w = i * 8 + wq;
      unsigned pk = bf16rne(T[2 * c2][w]) | (bf16rne(T[2 * c2 + 1][w]) << 16);
      op[w * 32 + c2] = pk;
    }
  } else {
    int t0 = (bid - BB * HH) * 256 + threadIdx.x;
    const int stride = 64 * 256;
    for (int i = t0; i < 72 * 64 * 4; i += stride) {
      int j = i & 3, o = (i >> 2) & 63, g = i >> 8;
      int k2 = g * 4 + j, t = k2 >> 5, jj = k2 & 31;
      unsigned lo = bf16rne(dc_w[o * KK + (2 * jj) * 9 + t]);
      unsigned hi = bf16rne(dc_w[o * KK + (2 * jj + 1) * 9 + t]);
      Bg[i] = (int)(lo | (hi << 16));
    }
    for (int i = t0; i < 72 * 32 * 4; i += stride) {
      int j = i & 3, o = (i >> 2) & 31, g = i >> 7;
      int k2 = g * 4 + j, t = k2 >> 5, jj = k2 & 31;
      unsigned pk = 0;
      if (o < NOFF) {
        unsigned lo = bf16rne(off_w[o * KK + (2 * jj) * 9 + t]);
        unsigned hi = bf16rne(off_w[o * KK + (2 * jj + 1) * 9 + t]);
        pk = lo | (hi << 16);
      }
      Bgo[i] = (int)pk;
    }
    if (t0 < 128) sums[t0] = 0.0f;   // sums + sumsq contiguous
  }
}

// phase-3 helpers: explicit double-buffered software pipeline.
__device__ __forceinline__ void prefetch_step(
    int4v& mv, int4v* L, int tval, int q, int n16,
    const int* __restrict__ Mw, const unsigned int* __restrict__ xbu) {
  mv = *(const int4v*)&Mw[(n16 * 9 + tval) * 4];
  unsigned o00 = mv.x & 0xffff, o01 = ((unsigned)mv.x) >> 16;
  unsigned o10 = mv.y & 0xffff, o11 = ((unsigned)mv.y) >> 16;
  const unsigned int* p00 = xbu + o00 * 32 + q * 4;
  const unsigned int* p01 = xbu + o01 * 32 + q * 4;
  const unsigned int* p10 = xbu + o10 * 32 + q * 4;
  const unsigned int* p11 = xbu + o11 * 32 + q * 4;
  L[0] = *(const int4v*)(p00);
  L[1] = *(const int4v*)(p01);
  L[2] = *(const int4v*)(p10);
  L[3] = *(const int4v*)(p11);
  L[4] = *(const int4v*)(p00 + 16);
  L[5] = *(const int4v*)(p01 + 16);
  L[6] = *(const int4v*)(p10 + 16);
  L[7] = *(const int4v*)(p11 + 16);
}

__device__ __forceinline__ void compute_step(
    const int4v& mv, const int4v* L, int tval, int q, int n16,
    const int* __restrict__ Bg, f32x4 (&acc)[4]) {
  f32x2 w00, w01, w10, w11;
  w00.x = __uint_as_float(((unsigned)mv.z) << 16);         w00.y = w00.x;
  w01.x = __uint_as_float(((unsigned)mv.z) & 0xffff0000u); w01.y = w01.x;
  w10.x = __uint_as_float(((unsigned)mv.w) << 16);         w10.y = w10.x;
  w11.x = __uint_as_float(((unsigned)mv.w) & 0xffff0000u); w11.y = w11.x;
#pragma unroll
  for (int s = 0; s < 2; ++s) {
    int4v d00 = L[s * 4 + 0], d01 = L[s * 4 + 1];
    int4v d10 = L[s * 4 + 2], d11 = L[s * 4 + 3];
    int4v av;
    {
      f32x2 sc = up2(d00.x) * w00;
      sc = up2(d01.x) * w01 + sc;
      sc = up2(d10.x) * w10 + sc;
      sc = up2(d11.x) * w11 + sc;
      av.x = (int)pk2(sc);
    }
    {
      f32x2 sc = up2(d00.y) * w00;
      sc = up2(d01.y) * w01 + sc;
      sc = up2(d10.y) * w10 + sc;
      sc = up2(d11.y) * w11 + sc;
      av.y = (int)pk2(sc);
    }
    {
      f32x2 sc = up2(d00.z) * w00;
      sc = up2(d01.z) * w01 + sc;
      sc = up2(d10.z) * w10 + sc;
      sc = up2(d11.z) * w11 + sc;
      av.z = (int)pk2(sc);
    }
    {
      f32x2 sc = up2(d00.w) * w00;
      sc = up2(d01.w) * w01 + sc;
      sc = up2(d10.w) * w10 + sc;
      sc = up2(d11.w) * w11 + sc;
      av.w = (int)pk2(sc);
    }
    short8 af = __builtin_bit_cast(short8, av);
    int g = (tval * 2 + s) * 4 + q;
#pragma unroll
    for (int nt = 0; nt < 4; ++nt) {
      int4v bv = *(const int4v*)&Bg[(g * 64 + nt * 16 + n16) * 4];
      short8 bfr = __builtin_bit_cast(short8, bv);
      acc[nt] = __builtin_amdgcn_mfma_f32_16x16x32_bf16(af, bfr, acc[nt], 0, 0, 0);
    }
  }
}

// Fused offset-conv + deform-conv + BN-stats, all-register im2col with
// double-buffered prefetch across the 9-tap loop.
__global__ __launch_bounds__(256) void conv_kernel(
    const unsigned int* __restrict__ xTu, const int* __restrict__ Bg,
    const int* __restrict__ Bgo, const float* __restrict__ off_b,
    const float* __restrict__ dc_b, float* __restrict__ ybuf,
    float* __restrict__ sums, float* __restrict__ sumsq) {
  __shared__ __align__(16) int M[4 * 144 * 4];    // 9.2 KB bilinear meta
  __shared__ float offL[4][NOFF][16];             // 4.6 KB offsets
  __shared__ float Ssum[256], Ssq[256];           // 2 KB stats

  int cg = threadIdx.x >> 6, lane = threadIdx.x & 63;
  int b = blockIdx.x >> 8, rem = blockIdx.x & 255;
  int h = rem >> 1, w0 = (rem & 1) * 64;
  int hw0 = h * WW + w0;
  int p0 = cg * 16;
  int n16 = lane & 15, q = lane >> 4;
  const unsigned int* xbu = xTu + (size_t)b * HWSZ * 32;

  // ---------- phase 1: offset conv, direct-register im2col (fully unrolled) ----------
  f32x4 acc2[2] = {f32x4{0, 0, 0, 0}, f32x4{0, 0, 0, 0}};
  int cxp = w0 + p0 + n16 - 1;
#pragma unroll
  for (int chunk = 0; chunk < 3; ++chunk) {
    int cy = h + chunk - 1;
    bool vy = (cy >= 0) && (cy < HH);
    int cys = min(max(cy, 0), HH - 1);
#pragma unroll
    for (int tl = 0; tl < 3; ++tl) {
      int cx = cxp + tl;
      bool v = vy && (cx >= 0) && (cx < WW);
      int cxs = min(max(cx, 0), WW - 1);
      const unsigned int* src = xbu + (cys * WW + cxs) * 32 + q * 4;
      int t = chunk * 3 + tl;
#pragma unroll
      for (int s = 0; s < 2; ++s) {
        int4v av = *(const int4v*)(src + s * 16);
        if (!v) { av.x = 0; av.y = 0; av.z = 0; av.w = 0; }
        short8 af = __builtin_bit_cast(short8, av);
        int g = (t * 2 + s) * 4 + q;
#pragma unroll
        for (int nt = 0; nt < 2; ++nt) {
          int4v bv = *(const int4v*)&Bgo[(g * 32 + nt * 16 + n16) * 4];
          short8 bfr = __builtin_bit_cast(short8, bv);
          acc2[nt] = __builtin_amdgcn_mfma_f32_16x16x32_bf16(af, bfr, acc2[nt], 0, 0, 0);
        }
      }
    }
  }
#pragma unroll
  for (int nt = 0; nt < 2; ++nt) {
    int o = nt * 16 + n16;
    if (o < NOFF) {
      float bv = off_b[o];
#pragma unroll
      for (int r = 0; r < 4; ++r) offL[cg][o][q * 4 + r] = acc2[nt][r] + bv;
    }
  }

  // ---------- phase 2: bilinear meta (wave-private) ----------
  int* Mw = M + cg * 144 * 4;
#pragma unroll
  for (int it = 0; it < 3; ++it) {
    int m = it * 64 + lane;
    if (m < 144) {
      int pxl = (unsigned)m / 9u;
      int t = m - pxl * 9;
      float dy = offL[cg][2 * t][pxl];
      float dx = offL[cg][2 * t + 1][pxl];
      float py = (float)(h + t / 3 - 1) + dy;
      float pxf = (float)(w0 + p0 + pxl + (t % 3) - 1) + dx;
      float fy0 = floorf(py), fx0 = floorf(pxf);
      float ay = py - fy0, ax = pxf - fx0;
      int iy0 = (int)fy0, ix0 = (int)fx0;
      int iy1 = iy0 + 1, ix1 = ix0 + 1;
      float wy0 = 1.0f - ay, wy1 = ay, wx0 = 1.0f - ax, wx1 = ax;
      if (!(iy0 >= 0 && iy0 < HH)) wy0 = 0.0f;
      if (!(iy1 >= 0 && iy1 < HH)) wy1 = 0.0f;
      if (!(ix0 >= 0 && ix0 < WW)) wx0 = 0.0f;
      if (!(ix1 >= 0 && ix1 < WW)) wx1 = 0.0f;
      int cy0 = min(max(iy0, 0), HH - 1), cy1 = min(max(iy1, 0), HH - 1);
      int cx0 = min(max(ix0, 0), WW - 1), cx1 = min(max(ix1, 0), WW - 1);
      int4v mv;
      mv.x = (cy0 * WW + cx0) | ((cy0 * WW + cx1) << 16);
      mv.y = (cy1 * WW + cx0) | ((cy1 * WW + cx1) << 16);
      mv.z = (int)(bf16rne(wy0 * wx0) | (bf16rne(wy0 * wx1) << 16));
      mv.w = (int)(bf16rne(wy1 * wx0) | (bf16rne(wy1 * wx1) << 16));
      *(int4v*)&Mw[m * 4] = mv;
    }
  }

  // ---------- phase 3: deform conv, pipelined register gather + MFMA ----------
  f32x4 acc[4] = {f32x4{0,0,0,0}, f32x4{0,0,0,0}, f32x4{0,0,0,0}, f32x4{0,0,0,0}};
  {
    int4v mvA, mvB;
    int4v LA[8], LB[8];
    prefetch_step(mvA, LA, 0, q, n16, Mw, xbu);
#pragma unroll 1
    for (int it = 0; it < 4; ++it) {
      prefetch_step(mvB, LB, 2 * it + 1, q, n16, Mw, xbu);
      compute_step(mvA, LA, 2 * it, q, n16, Bg, acc);
      prefetch_step(mvA, LA, 2 * it + 2, q, n16, Mw, xbu);
      compute_step(mvB, LB, 2 * it + 1, q, n16, Bg, acc);
    }
    compute_step(mvA, LA, 8, q, n16, Bg, acc);
  }

  // ---------- epilogue: y store + stats reduce ----------
#pragma unroll
  for (int nt = 0; nt < 4; ++nt) {
    int o = nt * 16 + n16;
    float bv = dc_b[o];
    float s = 0.0f, ss = 0.0f;
#pragma unroll
    for (int r0 = 0; r0 < 4; ++r0) {
      acc[nt][r0] += bv;
      s += acc[nt][r0];
      ss += acc[nt][r0] * acc[nt][r0];
    }
    *(f32x4*)(ybuf + (size_t)(b * OO + o) * HWSZ + hw0 + p0 + q * 4) = acc[nt];
    s += __shfl_xor(s, 16);  s += __shfl_xor(s, 32);
    ss += __shfl_xor(ss, 16); ss += __shfl_xor(ss, 32);
    if (lane < 16) {   // lane == n16
      Ssum[cg * 64 + nt * 16 + lane] = s;
      Ssq[cg * 64 + nt * 16 + lane] = ss;
    }
  }
  __syncthreads();
  if (threadIdx.x < 64) {
    float ts = 0.0f, tq = 0.0f;
#pragma unroll
    for (int wv = 0; wv < 4; ++wv) {
      ts += Ssum[wv * 64 + threadIdx.x];
      tq += Ssq[wv * 64 + threadIdx.x];
    }
    atomicAdd(&sums[threadIdx.x], ts);
    atomicAdd(&sumsq[threadIdx.x], tq);
  }
}

__global__ __launch_bounds__(256) void norm_kernel(
    const float* __restrict__ ybuf, const float* __restrict__ sums,
    const float* __restrict__ sumsq, const float* __restrict__ gamma,
    const float* __restrict__ beta, float* __restrict__ out) {
  int gid = blockIdx.x * 256 + threadIdx.x;
  int flat = gid << 2;
  int o = (flat >> 14) & 63;
  const float invN = 1.0f / (float)(BB * HWSZ);
  float mean = sums[o] * invN;
  float var = sumsq[o] * invN - mean * mean;
  float rstd = rsqrtf(var + EPS);
  float g = gamma[o] * rstd;
  float bta = beta[o] - mean * g;
  float4 v = ((const float4*)ybuf)[gid];
  float4 r;
  r.x = fmaxf(v.x * g + bta, 0.0f);
  r.y = fmaxf(v.y * g + bta, 0.0f);
  r.z = fmaxf(v.z * g + bta, 0.0f);
  r.w = fmaxf(v.w * g + bta, 0.0f);
  ((float4*)out)[gid] = r;
}

extern "C" void kernel_launch(void* const* d_in, const int* in_sizes, int n_in,
                              void* d_out, int out_size, void* d_ws, size_t ws_size,
                              hipStream_t stream) {
  const float* x     = (const float*)d_in[0];
  const float* off_w = (const float*)d_in[1];
  const float* off_b = (const float*)d_in[2];
  const float* dc_w  = (const float*)d_in[3];
  const float* dc_b  = (const float*)d_in[4];
  const float* gamma = (const float*)d_in[5];
  const float* beta  = (const float*)d_in[6];
  float* ws = (float*)d_ws;
  int*   Bg    = (int*)(ws + WS_BG);
  int*   Bgo   = (int*)(ws + WS_BGO);
  float* sums  = ws + WS_SUMS;
  float* sumsq = ws + WS_SUMSQ;
  float* ybuf  = ws + WS_YBUF;
  float* out = (float*)d_out;
  unsigned int* xTu = (unsigned int*)d_out;  // d_out doubles as NHWC-bf16 scratch

  prep_kernel<<<BB * HH + 64, 256, 0, stream>>>(x, off_w, dc_w, xTu, Bg, Bgo, sums);
  conv_kernel<<<BB * HWSZ / 64, 256, 0, stream>>>(xTu, Bg, Bgo, off_b, dc_b, ybuf, sums, sumsq);
  norm_kernel<<<BB * OO * HWSZ / (4 * 256), 256, 0, stream>>>(ybuf, sums, sumsq, gamma, beta, out);
}